// Round 5
// baseline (456.723 us; speedup 1.0000x reference)
//
#include <hip/hip_runtime.h>
#include <hip/hip_fp16.h>
#include <math.h>

// SelfAttentionModel: B=4, S=4096, H=1, E=256.
// Harness ABI: reference dtype is float16 -> harness provides fp32 inputs and
// expects fp32 output (only bf16/int32/fp32 decode paths exist).
// Factored form:
//   scores = Xq * M * Xk^T,      M   = Wq^T Wk / 16    (256x256, fp16 in ws)
//   out    = (P * Xv) * Wov^T,   Wov = Wo Wv           (256x256, fp16 in ws)
// Optional (ws_size permitting): Xk,Xv down-converted once to fp16 in ws so the
// attention working set (4 MB/batch) fits an XCD-pair's L2.

typedef __attribute__((ext_vector_type(8))) short short8;    // 8 fp16 = MFMA A/B frag
typedef __attribute__((ext_vector_type(4))) short short4v;
typedef __attribute__((ext_vector_type(4))) float floatx4;   // MFMA C/D frag
typedef __attribute__((ext_vector_type(4))) float float4v;

#define LOG2E 1.4426950408889634f

__device__ __forceinline__ short f2h(float f) {
    union { __half h; short s; } u; u.h = __float2half(f); return u.s;
}

__device__ __forceinline__ float row16_max(float v) {
    v = fmaxf(v, __shfl_xor(v, 1));
    v = fmaxf(v, __shfl_xor(v, 2));
    v = fmaxf(v, __shfl_xor(v, 4));
    v = fmaxf(v, __shfl_xor(v, 8));
    return v;
}
__device__ __forceinline__ float row16_sum(float v) {
    v += __shfl_xor(v, 1);
    v += __shfl_xor(v, 2);
    v += __shfl_xor(v, 4);
    v += __shfl_xor(v, 8);
    return v;
}

// ---------------------------------------------------------------------------
// prep: Wmt[a][b] = sum_f Wk[f][a]*Wq[f][b] / 16  (= M^T, B-operand layout)
//       Wov[f][e] = sum_j Wo[f][j]*Wv[j][e]
// ---------------------------------------------------------------------------
__global__ __launch_bounds__(256) void prep_kernel(
    const float* __restrict__ Wq, const float* __restrict__ Wk,
    const float* __restrict__ Wv, const float* __restrict__ Wo,
    short* __restrict__ Wmt, short* __restrict__ Wov)
{
    const int tid = threadIdx.x;
    const int blk = blockIdx.x;
    float acc = 0.f;
    if (blk < 256) {
        const int a = blk;
        #pragma unroll 4
        for (int f = 0; f < 256; ++f)
            acc += Wk[f * 256 + a] * Wq[f * 256 + tid];
        Wmt[a * 256 + tid] = f2h(acc * 0.0625f);
    } else {
        const int f = blk - 256;
        #pragma unroll 4
        for (int j = 0; j < 256; ++j)
            acc += Wo[f * 256 + j] * Wv[j * 256 + tid];
        Wov[f * 256 + tid] = f2h(acc);
    }
}

// elementwise fp32 -> fp16 (4 elems/thread)
__global__ __launch_bounds__(256) void cvt_kernel(
    const float* __restrict__ src, short* __restrict__ dst)
{
    const long i = ((long)blockIdx.x * 256 + threadIdx.x) * 4;
    float4v v = *(const float4v*)(src + i);
    short4v h;
    h[0] = f2h(v[0]); h[1] = f2h(v[1]); h[2] = f2h(v[2]); h[3] = f2h(v[3]);
    *(short4v*)(dst + i) = h;
}

// ---------------------------------------------------------------------------
// attn: fused Q'=Xq*Wmt^T prologue + flash attention + (P*Xv)*Wov^T epilogue.
// grid 256 = B(4) x qtiles(64); block 256 = 4 waves x 16 q-rows.
// USE16: K/V read from fp16 ws copies; else converted inline from fp32.
// ---------------------------------------------------------------------------
template <bool USE16>
__global__ __launch_bounds__(256) void attn_kernel(
    const float* __restrict__ Xq, const float* __restrict__ Xk32,
    const float* __restrict__ Xv32, const short* __restrict__ Kh,
    const short* __restrict__ Vh, const short* __restrict__ Wmt,
    const short* __restrict__ Wov, const float* __restrict__ bo,
    float* __restrict__ out)
{
    __shared__ short smem[64 * 264];  // 33 KB
    short* Kl  = smem;                // [32][264]
    short* Pl  = smem + 8448;         // 4 x [16][40] per-wave
    short* QOl = smem;                // [64][264] alias (pre-loop Q', post-loop O')

    const int tid = threadIdx.x;
    const int w = tid >> 6, lane = tid & 63, c = lane & 15, q = lane >> 4;
    const int x = blockIdx.x;
    const int xcd = x & 7;
    const int b = xcd >> 1;                      // batch pinned to an XCD pair
    const int qt = ((x >> 3) << 1) | (xcd & 1);  // 0..63
    const int wrow = b * 4096 + qt * 64 + w * 16;

    // ---- prologue: Q'[m][j] = sum_i Xq[m][i] * Wmt[j][i] ----
    short8 xa[8];
    {
        const float* xq = Xq + (long)(wrow + c) * 256;
        #pragma unroll
        for (int kb = 0; kb < 8; ++kb) {
            const float* p = xq + kb * 32 + q * 8;
            float4v lo = *(const float4v*)(p);
            float4v hi = *(const float4v*)(p + 4);
            short8 t;
            t[0] = f2h(lo[0]); t[1] = f2h(lo[1]); t[2] = f2h(lo[2]); t[3] = f2h(lo[3]);
            t[4] = f2h(hi[0]); t[5] = f2h(hi[1]); t[6] = f2h(hi[2]); t[7] = f2h(hi[3]);
            xa[kb] = t;
        }
    }
    floatx4 qa[16];
    #pragma unroll
    for (int f = 0; f < 16; ++f) qa[f] = (floatx4){0.f, 0.f, 0.f, 0.f};
    #pragma unroll
    for (int kb = 0; kb < 8; ++kb)
        #pragma unroll
        for (int f = 0; f < 16; ++f) {
            short8 wf = *(const short8*)(Wmt + (f * 16 + c) * 256 + kb * 32 + q * 8);
            qa[f] = __builtin_amdgcn_mfma_f32_16x16x32_f16(xa[kb], wf, qa[f], 0, 0, 0);
        }
    // C-layout -> LDS (own wave's 16 rows) -> read back A-layout
    #pragma unroll
    for (int f = 0; f < 16; ++f)
        #pragma unroll
        for (int r = 0; r < 4; ++r)
            QOl[(w * 16 + q * 4 + r) * 264 + f * 16 + c] = f2h(qa[f][r]);
    short8 qf[8];
    #pragma unroll
    for (int kb = 0; kb < 8; ++kb)
        qf[kb] = *(const short8*)(&QOl[(w * 16 + c) * 264 + kb * 32 + q * 8]);
    __syncthreads();  // Q' stage done before Kl/Pl reuse of smem

    floatx4 oacc[16];
    #pragma unroll
    for (int ef = 0; ef < 16; ++ef) oacc[ef] = (floatx4){0.f, 0.f, 0.f, 0.f};
    float mrow[4], lrow[4];
    #pragma unroll
    for (int r = 0; r < 4; ++r) { mrow[r] = -1e30f; lrow[r] = 0.f; }

    const long kvbase = (long)b * 4096 * 256;

    short8 kreg[4];
    #pragma unroll
    for (int i = 0; i < 4; ++i) {
        int cc = tid + i * 256;
        if (USE16) {
            kreg[i] = *(const short8*)(Kh + kvbase + (cc >> 5) * 256 + (cc & 31) * 8);
        } else {
            const float* p = Xk32 + kvbase + (cc >> 5) * 256 + (cc & 31) * 8;
            float4v lo = *(const float4v*)(p);
            float4v hi = *(const float4v*)(p + 4);
            short8 t;
            t[0] = f2h(lo[0]); t[1] = f2h(lo[1]); t[2] = f2h(lo[2]); t[3] = f2h(lo[3]);
            t[4] = f2h(hi[0]); t[5] = f2h(hi[1]); t[6] = f2h(hi[2]); t[7] = f2h(hi[3]);
            kreg[i] = t;
        }
    }

    for (int t = 0; t < 128; ++t) {
        #pragma unroll
        for (int i = 0; i < 4; ++i) {
            int cc = tid + i * 256;
            *(short8*)(&Kl[(cc >> 5) * 264 + (cc & 31) * 8]) = kreg[i];
        }
        __syncthreads();  // (A) Kl staged

        if (t + 1 < 128) {
            int kv0 = (t + 1) * 32;
            #pragma unroll
            for (int i = 0; i < 4; ++i) {
                int cc = tid + i * 256;
                if (USE16) {
                    kreg[i] = *(const short8*)(Kh + kvbase + (kv0 + (cc >> 5)) * 256 + (cc & 31) * 8);
                } else {
                    const float* p = Xk32 + kvbase + (long)(kv0 + (cc >> 5)) * 256 + (cc & 31) * 8;
                    float4v lo = *(const float4v*)(p);
                    float4v hi = *(const float4v*)(p + 4);
                    short8 tt;
                    tt[0] = f2h(lo[0]); tt[1] = f2h(lo[1]); tt[2] = f2h(lo[2]); tt[3] = f2h(lo[3]);
                    tt[4] = f2h(hi[0]); tt[5] = f2h(hi[1]); tt[6] = f2h(hi[2]); tt[7] = f2h(hi[3]);
                    kreg[i] = tt;
                }
            }
        }

        // Xv B-frags from global (L2-hot): B[n=ef*16+c][k=q*8+j]
        const long vtile = kvbase + (long)(t * 32 + q * 8) * 256 + c;
        short8 vf[16];
        #pragma unroll
        for (int ef = 0; ef < 16; ++ef)
            #pragma unroll
            for (int j = 0; j < 8; ++j)
                vf[ef][j] = USE16 ? Vh[vtile + j * 256 + ef * 16]
                                  : f2h(Xv32[vtile + j * 256 + ef * 16]);

        // scores = Q' * Xk_tile^T
        floatx4 s0f = (floatx4){0.f, 0.f, 0.f, 0.f};
        floatx4 s1f = (floatx4){0.f, 0.f, 0.f, 0.f};
        #pragma unroll
        for (int kb = 0; kb < 8; ++kb) {
            short8 k0 = *(const short8*)(&Kl[c * 264 + (kb * 4 + q) * 8]);
            short8 k1 = *(const short8*)(&Kl[(16 + c) * 264 + (kb * 4 + q) * 8]);
            s0f = __builtin_amdgcn_mfma_f32_16x16x32_f16(qf[kb], k0, s0f, 0, 0, 0);
            s1f = __builtin_amdgcn_mfma_f32_16x16x32_f16(qf[kb], k1, s1f, 0, 0, 0);
        }

        // online softmax per C-row (row = q*4+r)
        float alpha[4];
        #pragma unroll
        for (int r = 0; r < 4; ++r) {
            float mt_ = row16_max(fmaxf(s0f[r], s1f[r]));
            float mn = fmaxf(mrow[r], mt_);
            alpha[r] = exp2f((mrow[r] - mn) * LOG2E);
            float p0 = exp2f((s0f[r] - mn) * LOG2E);
            float p1 = exp2f((s1f[r] - mn) * LOG2E);
            s0f[r] = p0; s1f[r] = p1;
            lrow[r] = lrow[r] * alpha[r] + row16_sum(p0 + p1);
            mrow[r] = mn;
        }

        // P -> per-wave LDS (C-layout -> A-layout round trip)
        #pragma unroll
        for (int r = 0; r < 4; ++r) {
            Pl[w * 640 + (q * 4 + r) * 40 + c] = f2h(s0f[r]);
            Pl[w * 640 + (q * 4 + r) * 40 + 16 + c] = f2h(s1f[r]);
        }
        __syncthreads();  // (B) P visible; also fences Kl reads before next-iter writes

        #pragma unroll
        for (int ef = 0; ef < 16; ++ef)
            #pragma unroll
            for (int r = 0; r < 4; ++r)
                oacc[ef][r] *= alpha[r];

        short8 pf = *(const short8*)(&Pl[w * 640 + c * 40 + q * 8]);
        #pragma unroll
        for (int ef = 0; ef < 16; ++ef)
            oacc[ef] = __builtin_amdgcn_mfma_f32_16x16x32_f16(pf, vf[ef], oacc[ef], 0, 0, 0);
    }
    __syncthreads();  // all waves done with Kl/Pl before QOl reuse

    // ---- epilogue: O' -> LDS (A-layout), out = O' * Wov^T + bo (fp32 out) ----
    float inv[4];
    #pragma unroll
    for (int r = 0; r < 4; ++r) inv[r] = 1.f / lrow[r];
    #pragma unroll
    for (int ef = 0; ef < 16; ++ef)
        #pragma unroll
        for (int r = 0; r < 4; ++r)
            QOl[(w * 16 + q * 4 + r) * 264 + ef * 16 + c] = f2h(oacc[ef][r] * inv[r]);
    short8 of[8];
    #pragma unroll
    for (int kb = 0; kb < 8; ++kb)
        of[kb] = *(const short8*)(&QOl[(w * 16 + c) * 264 + kb * 32 + q * 8]);

    floatx4 acc2[16];
    #pragma unroll
    for (int f = 0; f < 16; ++f) acc2[f] = (floatx4){0.f, 0.f, 0.f, 0.f};
    #pragma unroll
    for (int kb = 0; kb < 8; ++kb)
        #pragma unroll
        for (int f = 0; f < 16; ++f) {
            short8 wof = *(const short8*)(Wov + (f * 16 + c) * 256 + kb * 32 + q * 8);
            acc2[f] = __builtin_amdgcn_mfma_f32_16x16x32_f16(of[kb], wof, acc2[f], 0, 0, 0);
        }
    #pragma unroll
    for (int f = 0; f < 16; ++f) {
        float bv = bo[f * 16 + c];
        #pragma unroll
        for (int r = 0; r < 4; ++r)
            out[(long)(wrow + q * 4 + r) * 256 + f * 16 + c] = acc2[f][r] + bv;
    }
}

extern "C" void kernel_launch(void* const* d_in, const int* in_sizes, int n_in,
                              void* d_out, int out_size, void* d_ws, size_t ws_size,
                              hipStream_t stream) {
    const float* q_in = (const float*)d_in[0];
    const float* k_in = (const float*)d_in[1];
    const float* v_in = (const float*)d_in[2];
    const float* Wq   = (const float*)d_in[3];
    const float* Wk   = (const float*)d_in[4];
    const float* Wv   = (const float*)d_in[5];
    const float* Wo   = (const float*)d_in[6];
    const float* bo   = (const float*)d_in[7];
    float* out = (float*)d_out;
    short* ws  = (short*)d_ws;

    short* Wmt = ws;           // [256][256] fp16, 128 KB
    short* Wov = ws + 65536;   // [256][256] fp16, 128 KB
    short* Kh  = ws + 131072;          // [4][4096][256] fp16, 8 MB
    short* Vh  = ws + 131072 + 4194304;// [4][4096][256] fp16, 8 MB
    const size_t need16 = (size_t)(131072 + 2 * 4194304) * 2;  // ~17 MB

    prep_kernel<<<512, 256, 0, stream>>>(Wq, Wk, Wv, Wo, Wmt, Wov);
    if (ws_size >= need16) {
        cvt_kernel<<<4096, 256, 0, stream>>>(k_in, Kh);
        cvt_kernel<<<4096, 256, 0, stream>>>(v_in, Vh);
        attn_kernel<true><<<256, 256, 0, stream>>>(q_in, k_in, v_in, Kh, Vh, Wmt, Wov, bo, out);
    } else {
        attn_kernel<false><<<256, 256, 0, stream>>>(q_in, k_in, v_in, nullptr, nullptr, Wmt, Wov, bo, out);
    }
}